// Round 4
// baseline (289.618 us; speedup 1.0000x reference)
//
#include <hip/hip_runtime.h>
#include <cmath>
#include <cstdint>

typedef __attribute__((ext_vector_type(8))) short short8;
typedef __attribute__((ext_vector_type(4))) float f32x4;

struct Lams { float v[8]; };

#define NC 8
#define NB 4
#define NT 8192
#define ND 64
#define CL 128               // chunk length (rows per block)
#define NK (NT / CL)         // 64 chunks per (dir,c,b)
#define NSLOT (2 * NC * NB * NK)   // 4096 chunk slots
#define LDP 68               // padded LDS row stride (f32) -> 2-way banks max

// packed f32x2 -> bf16x2 (RNE), gfx950 v_cvt_pk_bf16_f32
__device__ __forceinline__ uint32_t pk2(float lo, float hi) {
    uint32_t r;
    asm("v_cvt_pk_bf16_f32 %0, %1, %2" : "=v"(r) : "v"(lo), "v"(hi));
    return r;
}

__device__ __forceinline__ short8 cvt8(f32x4 a, f32x4 b) {
    union { short8 s8; uint32_t u[4]; } t;
    t.u[0] = pk2(a[0], a[1]);
    t.u[1] = pk2(a[2], a[3]);
    t.u[2] = pk2(b[0], b[1]);
    t.u[3] = pk2(b[2], b[3]);
    return t.s8;
}

// Fused: stage x->LDS once; MFMA logits from LDS; sigmoid epilogue gates
// in place (LDS); register-resident chunk scan; decoupled NON-CHAINED
// lookback with pipelined plain-load Horner; single final write.
// ws layout: int flags[NSLOT] @0; float E[NSLOT][ND] @16KiB.
__global__ __launch_bounds__(256, 4) void k1_fused(
    const float* __restrict__ x, const float* __restrict__ Wf,
    const float* __restrict__ bf, const float* __restrict__ Wb,
    const float* __restrict__ bb, float* __restrict__ out,
    int* __restrict__ flags, float* __restrict__ evals, Lams lams)
{
    __shared__ float xbuf[CL * LDP];    // x, overwritten in place by gated
    __shared__ float ends_lds[4][ND];   // per-wave sub-chunk ends
    __shared__ float hprev_lds[ND];     // resolved cross-chunk carry

    const int tid  = threadIdx.x;
    const int lane = tid & 63;
    const int w    = tid >> 6;          // wave 0..3

    int idx = blockIdx.x;
    const int k   = idx & (NK - 1); idx >>= 6;
    const int b   = idx & (NB - 1); idx >>= 2;
    const int c   = idx & (NC - 1); idx >>= 3;
    const int dir = idx;                // 0 fwd, 1 bwd

    const float lam = lams.v[c];
    const float* W    = (dir ? Wb : Wf) + c * ND * ND;
    const float* bias = (dir ? bb : bf) + c * ND;
    const float* xb   = x + (size_t)(c * NB + b) * NT * ND;
    float* ob = out + (size_t)dir * (size_t)(NC*NB*NT*ND)
                    + (size_t)(c * NB + b) * NT * ND;

    const int er = lane & 15;   // row/col within 16-tile
    const int ks = lane >> 4;   // k-segment 0..3

    const int tr0 = k * CL;
    const int r0  = w * 32;     // this wave's rows [r0, r0+32)

    // ---- stage x rows [r0, r0+32) into LDS (f32, coalesced, once) ----
    {
        const int sr = lane >> 4;          // row within group of 4
        const int sc = (lane & 15) * 4;    // f32 column
        #pragma unroll
        for (int g = 0; g < 8; ++g) {
            const int rl = r0 + g*4 + sr;
            const int tg = dir ? (NT-1 - (tr0 + rl)) : (tr0 + rl);
            f32x4 v = *reinterpret_cast<const f32x4*>(xb + (size_t)tg * ND + sc);
            *reinterpret_cast<f32x4*>(&xbuf[rl * LDP + sc]) = v;
        }
    }

    // ---- B fragments from W (L2-hot), bias ----
    short8 bfrag[4][2];
    #pragma unroll
    for (int et = 0; et < 4; ++et) {
        const float* wr = W + (et*16 + er) * ND + ks * 8;
        #pragma unroll
        for (int kk = 0; kk < 2; ++kk) {
            f32x4 lo = *reinterpret_cast<const f32x4*>(wr + kk*32);
            f32x4 hi = *reinterpret_cast<const f32x4*>(wr + kk*32 + 4);
            bfrag[et][kk] = cvt8(lo, hi);
        }
    }
    float bias_r[4];
    #pragma unroll
    for (int et = 0; et < 4; ++et) bias_r[et] = bias[et*16 + er];

    // ---- MFMA logits + sigmoid epilogue; gate xbuf in place ----
    #pragma unroll
    for (int u = 0; u < 2; ++u) {
        const int rl0 = r0 + u*16;
        short8 afrag[2];
        {
            const float* xr = &xbuf[(rl0 + er) * LDP + ks * 8];
            #pragma unroll
            for (int kk = 0; kk < 2; ++kk) {
                f32x4 lo = *reinterpret_cast<const f32x4*>(xr + kk*32);
                f32x4 hi = *reinterpret_cast<const f32x4*>(xr + kk*32 + 4);
                afrag[kk] = cvt8(lo, hi);
            }
        }
        #pragma unroll
        for (int et = 0; et < 4; ++et) {
            f32x4 acc = {0.f, 0.f, 0.f, 0.f};
            acc = __builtin_amdgcn_mfma_f32_16x16x32_bf16(afrag[0], bfrag[et][0], acc, 0,0,0);
            acc = __builtin_amdgcn_mfma_f32_16x16x32_bf16(afrag[1], bfrag[et][1], acc, 0,0,0);
            const int col = et*16 + er;
            #pragma unroll
            for (int r = 0; r < 4; ++r) {
                const int rl = rl0 + ks*4 + r;   // C/D: col=lane&15, row=(lane>>4)*4+r
                float z  = acc[r] + bias_r[et];
                float g  = __builtin_amdgcn_rcpf(1.0f + __expf(-z));
                float xv = xbuf[rl * LDP + col];
                xbuf[rl * LDP + col] = g * xv;   // same-lane read-then-write
            }
        }
    }
    // no barrier: wave w only ever touched rows [r0, r0+32)

    float lam32 = lam*lam; lam32*=lam32; lam32*=lam32; lam32*=lam32; lam32*=lam32;

    // ---- register-resident wave-local scan ----
    float hreg[32];
    {
        float h = 0.f;
        #pragma unroll
        for (int i = 0; i < 32; ++i) {
            float v = xbuf[(r0 + i) * LDP + lane];
            h = fmaf(h, lam, v);
            hreg[i] = h;
        }
        ends_lds[w][lane] = h;
    }
    __syncthreads();

    // ---- wave 3: publish local chunk end, decoupled lookback ----
    const int slot = blockIdx.x;   // (dir,c,b,k) == blockIdx layout
    if (w == 3) {
        float carry3 = 0.f;
        #pragma unroll
        for (int j = 0; j < 3; ++j) carry3 = fmaf(carry3, lam32, ends_lds[j][lane]);
        float E = fmaf(carry3, lam32, hreg[31]);   // local inclusive chunk end

        float Hprev = 0.f;
        if (c != 0) {
            // publish immediately (no dependence on other blocks)
            __hip_atomic_store(&evals[(size_t)slot * ND + lane], E,
                               __ATOMIC_RELAXED, __HIP_MEMORY_SCOPE_AGENT);
            __threadfence();
            if (lane == 0)
                __hip_atomic_store(&flags[slot], 1, __ATOMIC_RELEASE,
                                   __HIP_MEMORY_SCOPE_AGENT);
            if (k != 0) {
                const int base = slot - k;
                // parallel spin: one predecessor flag per lane (relaxed)
                if (lane < k) {
                    while (__hip_atomic_load(&flags[base + lane], __ATOMIC_RELAXED,
                                             __HIP_MEMORY_SCOPE_AGENT) == 0)
                        __builtin_amdgcn_s_sleep(1);
                }
                // one acquire fence, then PLAIN pipelined loads for Horner
                __builtin_amdgcn_fence(__ATOMIC_ACQUIRE, "agent");
                const float* eb = evals + (size_t)base * ND;
                float lam128 = lam32 * lam32; lam128 *= lam128;
                float P = 0.f;
                #pragma unroll 8
                for (int j = 0; j < k; ++j)
                    P = fmaf(P, lam128, eb[(size_t)j * ND + lane]);
                Hprev = P;
            }
        }
        hprev_lds[lane] = Hprev;
    }
    __syncthreads();

    // ---- total carry for this wave, final write from registers ----
    float carry = 0.f, pw = 1.f;
    for (int j = 0; j < w; ++j) {
        carry = fmaf(carry, lam32, ends_lds[j][lane]);
        pw *= lam32;
    }
    carry = fmaf(pw, hprev_lds[lane], carry);

    float f = lam;
    #pragma unroll
    for (int i = 0; i < 32; ++i) {
        const int tr = tr0 + r0 + i;
        const int tg = dir ? (NT-1 - tr) : tr;
        ob[(size_t)tg * ND + lane] = fmaf(f, carry, hreg[i]);
        f *= lam;
    }
}

extern "C" void kernel_launch(void* const* d_in, const int* in_sizes, int n_in,
                              void* d_out, int out_size, void* d_ws, size_t ws_size,
                              hipStream_t stream)
{
    const float* x  = (const float*)d_in[0];
    const float* Wf = (const float*)d_in[1];
    const float* bf = (const float*)d_in[2];
    const float* Wb = (const float*)d_in[3];
    const float* bb = (const float*)d_in[4];
    float* out = (float*)d_out;

    int*   flags = (int*)d_ws;                         // NSLOT ints (16 KiB)
    float* evals = (float*)((char*)d_ws + NSLOT * 4);  // NSLOT*ND floats (1 MiB)

    Lams lams;
    const double delta = 13.0 / 7.0;   // log2(8192)/(C-1)
    for (int c = 0; c < 8; ++c)
        lams.v[c] = (float)(1.0 - pow(2.0, -(double)c * delta));

    // reset flags every launch (graph-replay safe, on-stream)
    hipMemsetAsync(flags, 0, NSLOT * 4, stream);

    dim3 grid(NSLOT);   // 4096 blocks: (dir,c,b,k), k fastest
    k1_fused<<<grid, 256, 0, stream>>>(x, Wf, bf, Wb, bb, out, flags, evals, lams);
}

// Round 5
// 87.074 us; speedup vs baseline: 3.3261x; 3.3261x over previous
//
#include <hip/hip_runtime.h>
#include <cmath>
#include <cstdint>

typedef __attribute__((ext_vector_type(8))) short short8;
typedef __attribute__((ext_vector_type(4))) float f32x4;

struct Lams { float v[8]; };

#define NC 8
#define NB 4
#define NT 8192
#define ND 64
#define CL 128               // chunk length (rows per block)
#define NK (NT / CL)         // 64 chunks per (dir,c,b)
#define NSLOT (2 * NC * NB * NK)   // 4096 chunk slots
#define LDP 68               // padded LDS row stride (f32)

// packed f32x2 -> bf16x2 (RNE), gfx950 v_cvt_pk_bf16_f32
__device__ __forceinline__ uint32_t pk2(float lo, float hi) {
    uint32_t r;
    asm("v_cvt_pk_bf16_f32 %0, %1, %2" : "=v"(r) : "v"(lo), "v"(hi));
    return r;
}

__device__ __forceinline__ short8 cvt8(f32x4 a, f32x4 b) {
    union { short8 s8; uint32_t u[4]; } t;
    t.u[0] = pk2(a[0], a[1]);
    t.u[1] = pk2(a[2], a[3]);
    t.u[2] = pk2(b[0], b[1]);
    t.u[3] = pk2(b[2], b[3]);
    return t.s8;
}

__device__ __forceinline__ float ld_rlx(const float* p) {
    return __hip_atomic_load(p, __ATOMIC_RELAXED, __HIP_MEMORY_SCOPE_AGENT);
}

// Fused: stage x->LDS; MFMA logits; sigmoid gates in place; register
// chunk scan; decoupled NON-CHAINED lookback using ONLY relaxed agent
// atomics (no fences -> no L2 invalidate/writeback storms); single write.
// ws layout: int flags[NSLOT] @0; float E[NSLOT][ND] @16KiB.
__global__ __launch_bounds__(256, 4) void k1_fused(
    const float* __restrict__ x, const float* __restrict__ Wf,
    const float* __restrict__ bf, const float* __restrict__ Wb,
    const float* __restrict__ bb, float* __restrict__ out,
    int* __restrict__ flags, float* __restrict__ evals, Lams lams)
{
    __shared__ float xbuf[CL * LDP];    // x, overwritten in place by gated
    __shared__ float ends_lds[4][ND];   // per-wave sub-chunk ends
    __shared__ float hprev_lds[ND];     // resolved cross-chunk carry

    const int tid  = threadIdx.x;
    const int lane = tid & 63;
    const int w    = tid >> 6;          // wave 0..3

    int idx = blockIdx.x;
    const int k   = idx & (NK - 1); idx >>= 6;
    const int b   = idx & (NB - 1); idx >>= 2;
    const int c   = idx & (NC - 1); idx >>= 3;
    const int dir = idx;                // 0 fwd, 1 bwd

    const float lam = lams.v[c];
    const float* W    = (dir ? Wb : Wf) + c * ND * ND;
    const float* bias = (dir ? bb : bf) + c * ND;
    const float* xb   = x + (size_t)(c * NB + b) * NT * ND;
    float* ob = out + (size_t)dir * (size_t)(NC*NB*NT*ND)
                    + (size_t)(c * NB + b) * NT * ND;

    const int er = lane & 15;   // row/col within 16-tile
    const int ks = lane >> 4;   // k-segment 0..3

    const int tr0 = k * CL;
    const int r0  = w * 32;     // this wave's rows [r0, r0+32)

    // ---- stage x rows [r0, r0+32) into LDS (f32, coalesced, once) ----
    {
        const int sr = lane >> 4;          // row within group of 4
        const int sc = (lane & 15) * 4;    // f32 column
        #pragma unroll
        for (int g = 0; g < 8; ++g) {
            const int rl = r0 + g*4 + sr;
            const int tg = dir ? (NT-1 - (tr0 + rl)) : (tr0 + rl);
            f32x4 v = *reinterpret_cast<const f32x4*>(xb + (size_t)tg * ND + sc);
            *reinterpret_cast<f32x4*>(&xbuf[rl * LDP + sc]) = v;
        }
    }

    // ---- B fragments from W (L2-hot), bias ----
    short8 bfrag[4][2];
    #pragma unroll
    for (int et = 0; et < 4; ++et) {
        const float* wr = W + (et*16 + er) * ND + ks * 8;
        #pragma unroll
        for (int kk = 0; kk < 2; ++kk) {
            f32x4 lo = *reinterpret_cast<const f32x4*>(wr + kk*32);
            f32x4 hi = *reinterpret_cast<const f32x4*>(wr + kk*32 + 4);
            bfrag[et][kk] = cvt8(lo, hi);
        }
    }
    float bias_r[4];
    #pragma unroll
    for (int et = 0; et < 4; ++et) bias_r[et] = bias[et*16 + er];

    // ---- MFMA logits + sigmoid epilogue; gate xbuf in place ----
    #pragma unroll
    for (int u = 0; u < 2; ++u) {
        const int rl0 = r0 + u*16;
        short8 afrag[2];
        {
            const float* xr = &xbuf[(rl0 + er) * LDP + ks * 8];
            #pragma unroll
            for (int kk = 0; kk < 2; ++kk) {
                f32x4 lo = *reinterpret_cast<const f32x4*>(xr + kk*32);
                f32x4 hi = *reinterpret_cast<const f32x4*>(xr + kk*32 + 4);
                afrag[kk] = cvt8(lo, hi);
            }
        }
        #pragma unroll
        for (int et = 0; et < 4; ++et) {
            f32x4 acc = {0.f, 0.f, 0.f, 0.f};
            acc = __builtin_amdgcn_mfma_f32_16x16x32_bf16(afrag[0], bfrag[et][0], acc, 0,0,0);
            acc = __builtin_amdgcn_mfma_f32_16x16x32_bf16(afrag[1], bfrag[et][1], acc, 0,0,0);
            const int col = et*16 + er;
            #pragma unroll
            for (int r = 0; r < 4; ++r) {
                const int rl = rl0 + ks*4 + r;   // C/D: col=lane&15, row=(lane>>4)*4+r
                float z  = acc[r] + bias_r[et];
                float g  = __builtin_amdgcn_rcpf(1.0f + __expf(-z));
                float xv = xbuf[rl * LDP + col];
                xbuf[rl * LDP + col] = g * xv;   // same-lane read-then-write
            }
        }
    }
    // no barrier: wave w only ever touched rows [r0, r0+32)

    float lam32 = lam*lam; lam32*=lam32; lam32*=lam32; lam32*=lam32; lam32*=lam32;

    // ---- register-resident wave-local scan ----
    float hreg[32];
    {
        float h = 0.f;
        #pragma unroll
        for (int i = 0; i < 32; ++i) {
            float v = xbuf[(r0 + i) * LDP + lane];
            h = fmaf(h, lam, v);
            hreg[i] = h;
        }
        ends_lds[w][lane] = h;
    }
    __syncthreads();

    // ---- wave 3: publish local chunk end, fence-free decoupled lookback
    const int slot = blockIdx.x;   // (dir,c,b,k) == blockIdx layout
    if (w == 3) {
        float carry3 = 0.f;
        #pragma unroll
        for (int j = 0; j < 3; ++j) carry3 = fmaf(carry3, lam32, ends_lds[j][lane]);
        float E = fmaf(carry3, lam32, hreg[31]);   // local inclusive chunk end

        float Hprev = 0.f;
        if (c != 0) {
            // publish E via relaxed agent atomics (bypass L2, no fence)
            __hip_atomic_store(&evals[(size_t)slot * ND + lane], E,
                               __ATOMIC_RELAXED, __HIP_MEMORY_SCOPE_AGENT);
            // hand-rolled release: stores ack'd at coherence point first
            asm volatile("s_waitcnt vmcnt(0)" ::: "memory");
            if (lane == 0)
                __hip_atomic_store(&flags[slot], 1, __ATOMIC_RELAXED,
                                   __HIP_MEMORY_SCOPE_AGENT);
            if (k != 0) {
                const int base = slot - k;
                // parallel spin: one predecessor flag per lane, relaxed,
                // moderate backoff (no cache-maintenance ops anywhere)
                if (lane < k) {
                    while (__hip_atomic_load(&flags[base + lane], __ATOMIC_RELAXED,
                                             __HIP_MEMORY_SCOPE_AGENT) == 0)
                        __builtin_amdgcn_s_sleep(8);
                }
                // Horner over predecessors' ends via relaxed atomic loads
                const float* eb = evals + (size_t)base * ND;
                float lam128 = lam32 * lam32; lam128 *= lam128;
                float P = 0.f;
                #pragma unroll 8
                for (int j = 0; j < k; ++j)
                    P = fmaf(P, lam128, ld_rlx(eb + (size_t)j * ND + lane));
                Hprev = P;
            }
        }
        hprev_lds[lane] = Hprev;
    }
    __syncthreads();

    // ---- total carry for this wave, final write from registers ----
    float carry = 0.f, pw = 1.f;
    for (int j = 0; j < w; ++j) {
        carry = fmaf(carry, lam32, ends_lds[j][lane]);
        pw *= lam32;
    }
    carry = fmaf(pw, hprev_lds[lane], carry);

    float f = lam;
    #pragma unroll
    for (int i = 0; i < 32; ++i) {
        const int tr = tr0 + r0 + i;
        const int tg = dir ? (NT-1 - tr) : tr;
        ob[(size_t)tg * ND + lane] = fmaf(f, carry, hreg[i]);
        f *= lam;
    }
}

extern "C" void kernel_launch(void* const* d_in, const int* in_sizes, int n_in,
                              void* d_out, int out_size, void* d_ws, size_t ws_size,
                              hipStream_t stream)
{
    const float* x  = (const float*)d_in[0];
    const float* Wf = (const float*)d_in[1];
    const float* bf = (const float*)d_in[2];
    const float* Wb = (const float*)d_in[3];
    const float* bb = (const float*)d_in[4];
    float* out = (float*)d_out;

    int*   flags = (int*)d_ws;                         // NSLOT ints (16 KiB)
    float* evals = (float*)((char*)d_ws + NSLOT * 4);  // NSLOT*ND floats (1 MiB)

    Lams lams;
    const double delta = 13.0 / 7.0;   // log2(8192)/(C-1)
    for (int c = 0; c < 8; ++c)
        lams.v[c] = (float)(1.0 - pow(2.0, -(double)c * delta));

    // reset flags every launch (graph-replay safe, on-stream)
    hipMemsetAsync(flags, 0, NSLOT * 4, stream);

    dim3 grid(NSLOT);   // 4096 blocks: (dir,c,b,k), k fastest
    k1_fused<<<grid, 256, 0, stream>>>(x, Wf, bf, Wb, bb, out, flags, evals, lams);
}